// Round 4
// baseline (149.474 us; speedup 1.0000x reference)
//
#include <hip/hip_runtime.h>
#include <hip/hip_bf16.h>

// ---------------------------------------------------------------------------
// UncertaintyAwareQNetwork: E=5 ensemble x NS=10 MC samples, B=4096 rows.
// Pipeline (3 dispatches):
//   prep:   state->bf16, realized weights (MFMA-frag-major) + fused KL partials
//   mlp:    fused 3-layer MFMA kernel, 256x256 block tile, in-place LDS,
//           weights read once per 256 rows, XCD es-affinity swizzle
//   heads:  ensemble stats + uncertainty/risk heads + KL final
// y2 layout: [b][es*20 + o] f32 (row = 1000 floats) for coalesced heads reads.
// ---------------------------------------------------------------------------

typedef __bf16 bf16x8 __attribute__((ext_vector_type(8)));
typedef float f32x4 __attribute__((ext_vector_type(4)));
typedef unsigned short u16x4 __attribute__((ext_vector_type(4)));
typedef unsigned short u16x8 __attribute__((ext_vector_type(8)));

__device__ __forceinline__ unsigned short f2bf(float f) {
  unsigned int u = __builtin_bit_cast(unsigned int, f);
  u += 0x7fffu + ((u >> 16) & 1u);
  return (unsigned short)(u >> 16);
}

__device__ __forceinline__ float softplus_f(float x) {
  return (x > 20.f) ? x : __logf(1.f + __expf(x));
}

__device__ __forceinline__ float klterm(float m, float sg) {
  return -__logf(sg) + (sg * sg + m * m) * 0.5f - 0.5f;
}

__device__ __forceinline__ f32x4 mfma16(bf16x8 a, bf16x8 b, f32x4 c) {
  return __builtin_amdgcn_mfma_f32_16x16x32_bf16(a, b, c, 0, 0, 0);
}

// ------------------- prep bodies (fused into one kernel) --------------------

__device__ __forceinline__ void scvt_body(int gid, const float* __restrict__ s,
                                          unsigned short* __restrict__ d) {
  const f32x4* p = (const f32x4*)(s + (size_t)gid * 8);
  f32x4 x0 = p[0], x1 = p[1];
  u16x8 v = {f2bf(x0.x), f2bf(x0.y), f2bf(x0.z), f2bf(x0.w),
             f2bf(x1.x), f2bf(x1.y), f2bf(x1.z), f2bf(x1.w)};
  *(u16x8*)(d + (size_t)gid * 8) = v;
}

// frag id = (es*(OPAD/16) + osub)*8 + kt ; lane l holds
// W[o = osub*16 + l%16][i = kt*32 + (l/16)*8 + 0..7]
// Returns this thread's KL partial (counted only for s==0 to avoid 10x).
template <int O, int OPAD>
__device__ __forceinline__ float wgen_body(int gid, const float* __restrict__ wmu,
                                           const float* __restrict__ wrho,
                                           const float* __restrict__ weps,
                                           char* __restrict__ wf) {
  int es = gid / (OPAD * 32);
  int rem = gid - es * (OPAD * 32);
  int o = rem >> 5;
  int i8 = (rem & 31) * 8;
  int e = es / 10, s = es - e * 10;
  float v[8];
  float kl = 0.f;
  if (O == OPAD || o < O) {
    const float* mu = wmu + ((size_t)(e * O + o)) * 256 + i8;
    const float* rho = wrho + ((size_t)(e * O + o)) * 256 + i8;
    const float* eps = weps + ((size_t)((e * 10 + s) * O + o)) * 256 + i8;
#pragma unroll
    for (int j = 0; j < 8; ++j) {
      float m = mu[j];
      float sg = softplus_f(rho[j]);
      v[j] = m + sg * eps[j];
      if (s == 0) kl += klterm(m, sg);
    }
  } else {
#pragma unroll
    for (int j = 0; j < 8; ++j) v[j] = 0.f;
  }
  u16x8 pk = {f2bf(v[0]), f2bf(v[1]), f2bf(v[2]), f2bf(v[3]),
              f2bf(v[4]), f2bf(v[5]), f2bf(v[6]), f2bf(v[7])};
  int osub = o >> 4, om = o & 15, kt = i8 >> 5, jj = (i8 >> 3) & 3;
  int lane = jj * 16 + om;
  *(u16x8*)(wf + (size_t)(((es * (OPAD / 16) + osub) * 8 + kt) * 64 + lane) * 16) = pk;
  return kl;
}

__global__ __launch_bounds__(256) void prep_kernel(
    const float* __restrict__ state, unsigned short* __restrict__ stateb,
    const float* __restrict__ wmu0, const float* __restrict__ wrho0,
    const float* __restrict__ weps0, char* __restrict__ W0f,
    const float* __restrict__ wmu1, const float* __restrict__ wrho1,
    const float* __restrict__ weps1, char* __restrict__ W1f,
    const float* __restrict__ wmu2, const float* __restrict__ wrho2,
    const float* __restrict__ weps2, char* __restrict__ W2f,
    const float* __restrict__ bmu0, const float* __restrict__ brho0,
    const float* __restrict__ beps0, const float* __restrict__ bmu1,
    const float* __restrict__ brho1, const float* __restrict__ beps1,
    const float* __restrict__ bmu2, const float* __restrict__ brho2,
    const float* __restrict__ beps2, float* __restrict__ bias0,
    float* __restrict__ bias1, float* __restrict__ bias2,
    float* __restrict__ partials) {
  int bid = blockIdx.x, t = threadIdx.x;
  float kl = 0.f;
  if (bid < 512) {
    scvt_body(bid * 256 + t, state, stateb);
  } else if (bid < 2112) {
    kl = wgen_body<256, 256>((bid - 512) * 256 + t, wmu0, wrho0, weps0, W0f);
  } else if (bid < 3712) {
    kl = wgen_body<256, 256>((bid - 2112) * 256 + t, wmu1, wrho1, weps1, W1f);
  } else if (bid < 3912) {
    kl = wgen_body<18, 32>((bid - 3712) * 256 + t, wmu2, wrho2, weps2, W2f);
  } else {
    int gid = (bid - 3912) * 256 + t;
    if (gid < 12800) {
      int es = gid >> 8, o = gid & 255, e = es / 10, s = es - e * 10;
      float m = bmu0[e * 256 + o];
      float sg = softplus_f(brho0[e * 256 + o]);
      bias0[gid] = m + sg * beps0[(e * 10 + s) * 256 + o];
      if (s == 0) kl = klterm(m, sg);
    } else if (gid < 25600) {
      int id = gid - 12800;
      int es = id >> 8, o = id & 255, e = es / 10, s = es - e * 10;
      float m = bmu1[e * 256 + o];
      float sg = softplus_f(brho1[e * 256 + o]);
      bias1[id] = m + sg * beps1[(e * 10 + s) * 256 + o];
      if (s == 0) kl = klterm(m, sg);
    } else if (gid < 27200) {
      int id = gid - 25600;
      int es = id >> 5, o = id & 31, e = es / 10, s = es - e * 10;
      if (o < 18) {
        float m = bmu2[e * 18 + o];
        float sg = softplus_f(brho2[e * 18 + o]);
        bias2[id] = m + sg * beps2[(e * 10 + s) * 18 + o];
        if (s == 0) kl = klterm(m, sg);
      } else {
        bias2[id] = 0.f;
      }
    }
  }
  // uniform block reduce of kl partials
#pragma unroll
  for (int m = 32; m >= 1; m >>= 1) kl += __shfl_xor(kl, m);
  __shared__ float wsum[4];
  if ((t & 63) == 0) wsum[t >> 6] = kl;
  __syncthreads();
  if (t == 0) partials[bid] = wsum[0] + wsum[1] + wsum[2] + wsum[3];
}

// ------------------------------ fused MLP ------------------------------------
// Block tile: 256 rows x 256 outs. 8 waves = 4 o-groups (og) x 2 row-groups (bg).
// Wave tile: 64 outs x 128 rows -> acc[4][8]. Weights (A-frags) from L2, read
// once per block; activations (B-frags) from LDS, overwritten in place.
template <int OG_BYTES>  // = 8192, bytes per osub-group of 4 subtiles? (fixed)
__device__ __forceinline__ void mlp_layer256(const char* __restrict__ wf_og,
                                             const float* __restrict__ bias_es,
                                             int obase, char* __restrict__ bufh,
                                             int lane) {
  f32x4 acc[4][8];
  f32x4 zero = {0.f, 0.f, 0.f, 0.f};
#pragma unroll
  for (int ot = 0; ot < 4; ++ot)
#pragma unroll
    for (int bi = 0; bi < 8; ++bi) acc[ot][bi] = zero;

#pragma unroll
  for (int kt = 0; kt < 8; ++kt) {
    bf16x8 bfr[8], afr[4];
#pragma unroll
    for (int bi = 0; bi < 8; ++bi)
      bfr[bi] = *(const bf16x8*)(bufh + (bi * 8 + kt) * 1024 + lane * 16);
#pragma unroll
    for (int ot = 0; ot < 4; ++ot)
      afr[ot] = *(const bf16x8*)(wf_og + (ot * 8 + kt) * 1024 + lane * 16);
    __builtin_amdgcn_s_setprio(1);
#pragma unroll
    for (int ot = 0; ot < 4; ++ot)
#pragma unroll
      for (int bi = 0; bi < 8; ++bi)
        acc[ot][bi] = mfma16(afr[ot], bfr[bi], acc[ot][bi]);
    __builtin_amdgcn_s_setprio(0);
  }
  __syncthreads();  // all reads of buf complete before in-place overwrite

  int g = lane >> 4, lm = lane & 15;
#pragma unroll
  for (int ot = 0; ot < 4; ++ot) {
    int i0 = obase + ot * 16 + 4 * g;
    f32x4 bv = *(const f32x4*)(bias_es + i0);
    int ktp = i0 >> 5;
    int lanep = ((i0 & 31) >> 3) * 16 + lm;
    int byo = (i0 & 7) * 2;
#pragma unroll
    for (int bi = 0; bi < 8; ++bi) {
      float v0 = fmaxf(acc[ot][bi].x + bv.x, 0.f);
      float v1 = fmaxf(acc[ot][bi].y + bv.y, 0.f);
      float v2 = fmaxf(acc[ot][bi].z + bv.z, 0.f);
      float v3 = fmaxf(acc[ot][bi].w + bv.w, 0.f);
      u16x4 pk = {f2bf(v0), f2bf(v1), f2bf(v2), f2bf(v3)};
      *(u16x4*)(bufh + (bi * 8 + ktp) * 1024 + lanep * 16 + byo) = pk;
    }
  }
  __syncthreads();  // writes visible before next layer reads
}

__global__ __launch_bounds__(512, 2) void mlp_fused(
    const unsigned short* __restrict__ stateb, const char* __restrict__ W0f,
    const char* __restrict__ W1f, const char* __restrict__ W2f,
    const float* __restrict__ bias0, const float* __restrict__ bias1,
    const float* __restrict__ bias2, float* __restrict__ y2) {
  __shared__ char buf[131072];  // 256 rows x 256 cols bf16 as 128 1KB frags
  int tid = threadIdx.x, w = tid >> 6, lane = tid & 63;

  // XCD-chunked bijective swizzle: 800 = 8 XCD * 100; same-es blocks share L2.
  int bid = blockIdx.x;
  int lin = (bid & 7) * 100 + (bid >> 3);
  int es = lin >> 4, b0 = (lin & 15) * 256;
  int og = w & 3, bg = w >> 2;

  // stage state tile [256 rows][256] as 128 B-frags
#pragma unroll
  for (int it = 0; it < 16; ++it) {
    int F = it * 8 + w, bt = F >> 3, kt = F & 7;
    const unsigned short* src =
        stateb + (size_t)(b0 + bt * 16 + (lane & 15)) * 256 + kt * 32 + (lane >> 4) * 8;
    *(u16x8*)(buf + F * 1024 + lane * 16) = *(const u16x8*)src;
  }
  __syncthreads();

  char* bufh = buf + bg * 65536;  // this wave's row-half
  mlp_layer256<8192>(W0f + (size_t)(es * 16 + og * 4) * 8192, bias0 + es * 256,
                     og * 64, bufh, lane);
  mlp_layer256<8192>(W1f + (size_t)(es * 16 + og * 4) * 8192, bias1 + es * 256,
                     og * 64, bufh, lane);

  // layer 2: O padded to 32; wave w handles row-subtiles {2w, 2w+1}, both osub
  f32x4 zero = {0.f, 0.f, 0.f, 0.f};
  f32x4 acc2[2][2] = {{zero, zero}, {zero, zero}};
  const char* w2 = W2f + (size_t)es * 16384;
#pragma unroll
  for (int kt = 0; kt < 8; ++kt) {
    bf16x8 bf0 = *(const bf16x8*)(buf + ((2 * w) * 8 + kt) * 1024 + lane * 16);
    bf16x8 bf1 = *(const bf16x8*)(buf + ((2 * w + 1) * 8 + kt) * 1024 + lane * 16);
    bf16x8 a0 = *(const bf16x8*)(w2 + kt * 1024 + lane * 16);
    bf16x8 a1 = *(const bf16x8*)(w2 + (8 + kt) * 1024 + lane * 16);
    acc2[0][0] = mfma16(a0, bf0, acc2[0][0]);
    acc2[0][1] = mfma16(a0, bf1, acc2[0][1]);
    acc2[1][0] = mfma16(a1, bf0, acc2[1][0]);
    acc2[1][1] = mfma16(a1, bf1, acc2[1][1]);
  }
  int g = lane >> 4, lm = lane & 15;
  f32x4 bv = *(const f32x4*)(bias2 + es * 32 + 4 * g);
  float b16 = bias2[es * 32 + 16], b17 = bias2[es * 32 + 17];
#pragma unroll
  for (int bp = 0; bp < 2; ++bp) {
    int b_idx = b0 + (2 * w + bp) * 16 + lm;
    f32x4 o4 = {acc2[0][bp].x + bv.x, acc2[0][bp].y + bv.y,
                acc2[0][bp].z + bv.z, acc2[0][bp].w + bv.w};
    *(f32x4*)(y2 + (size_t)b_idx * 1000 + es * 20 + 4 * g) = o4;
    if (g == 0) {
      float2 o2 = {acc2[1][bp].x + b16, acc2[1][bp].y + b17};
      *(float2*)(y2 + (size_t)b_idx * 1000 + es * 20 + 16) = o2;
    }
  }
}

// ------------- heads (with fused ensemble stats + KL final) ------------------
__global__ __launch_bounds__(256) void heads_kernel(
    const float* __restrict__ y2, const float* __restrict__ partials,
    const float* __restrict__ uh_w1, const float* __restrict__ uh_b1,
    const float* __restrict__ uh_w2, const float* __restrict__ uh_b2,
    const float* __restrict__ rh_w1, const float* __restrict__ rh_b1,
    const float* __restrict__ rh_w2, const float* __restrict__ rh_b2,
    float* __restrict__ out) {
  int b = blockIdx.x, t = threadIdx.x;
  if (b == 4096) {  // KL final reduce
    if (t < 64) {
      float acc = 0.f;
      for (int i = t; i < 4019; i += 64) acc += partials[i];
#pragma unroll
      for (int m = 32; m >= 1; m >>= 1) acc += __shfl_xor(acc, m);
      if (t == 0) out[446464] = acc * 0.2f;
    }
    return;
  }

  __shared__ float ysh[1000];
  __shared__ float qsE[90];
  __shared__ float rin[54];
  __shared__ float h[256];

  // coalesced row load: 1000 floats
  if (t < 250) *(f32x4*)(ysh + t * 4) = *(const f32x4*)(y2 + (size_t)b * 1000 + t * 4);
  __syncthreads();

  // per-(a,e) MC mean over s
  if (t < 90) {
    int a = t / 5, e = t - (t / 5) * 5;
    float v = 0.f;
#pragma unroll
    for (int s = 0; s < 10; ++s) v += ysh[(e * 10 + s) * 20 + a];
    qsE[t] = v * 0.1f;
  }
  __syncthreads();
  if (t < 18) {
    float qs = 0.f, qq = 0.f;
#pragma unroll
    for (int e = 0; e < 5; ++e) {
      float v = qsE[t * 5 + e];
      qs += v;
      qq += v * v;
    }
    float mean = qs * 0.2f;
    float var = fmaxf((qq - 5.f * mean * mean) * 0.25f, 0.f);
    rin[t] = mean;
    rin[18 + t] = var;
    out[b * 18 + t] = mean;
    out[73728 + b * 18 + t] = var;
  }
  __syncthreads();

  // uncertainty hidden layer
  {
    float acc = uh_b1[t];
    const f32x4* wr = (const f32x4*)(uh_w1 + t * 36);
#pragma unroll
    for (int j = 0; j < 9; ++j) {
      f32x4 wv = wr[j];
      acc += wv.x * rin[j * 4] + wv.y * rin[j * 4 + 1] + wv.z * rin[j * 4 + 2] +
             wv.w * rin[j * 4 + 3];
    }
    h[t] = fmaxf(acc, 0.f);
  }
  __syncthreads();

  int w = t >> 6, lane = t & 63;
  for (int idx = 0; idx < 5; ++idx) {
    int a = idx * 4 + w;
    if (a < 18) {
      float p = 0.f;
#pragma unroll
      for (int j = 0; j < 4; ++j) p += h[lane + 64 * j] * uh_w2[a * 256 + lane + 64 * j];
#pragma unroll
      for (int m = 32; m >= 1; m >>= 1) p += __shfl_xor(p, m);
      if (lane == 0) {
        float alea = softplus_f(p + uh_b2[a]);
        float qm = rin[a], epi = rin[18 + a];
        float tu = epi + alea;
        float s2 = 2.f * sqrtf(tu);
        out[2 * 73728 + b * 18 + a] = alea;
        out[3 * 73728 + b * 18 + a] = tu;
        out[4 * 73728 + b * 18 + a] = qm - s2;
        out[5 * 73728 + b * 18 + a] = qm + s2;
        rin[36 + a] = alea;
      }
    }
  }
  __syncthreads();

  // risk hidden layer
  {
    float acc = rh_b1[t];
    const float2* wr2 = (const float2*)(rh_w1 + t * 54);
#pragma unroll
    for (int j = 0; j < 27; ++j) {
      float2 wv = wr2[j];
      acc += wv.x * rin[j * 2] + wv.y * rin[j * 2 + 1];
    }
    h[t] = fmaxf(acc, 0.f);
  }
  __syncthreads();
  if (w == 0) {
    float p = 0.f;
#pragma unroll
    for (int j = 0; j < 4; ++j) p += h[lane + 64 * j] * rh_w2[lane + 64 * j];
#pragma unroll
    for (int m = 32; m >= 1; m >>= 1) p += __shfl_xor(p, m);
    if (lane == 0) out[6 * 73728 + b] = p + rh_b2[0];
  }
}

// ------------------------------ launch ---------------------------------------
extern "C" void kernel_launch(void* const* d_in, const int* in_sizes, int n_in,
                              void* d_out, int out_size, void* d_ws, size_t ws_size,
                              hipStream_t stream) {
  const float* state = (const float*)d_in[0];
  const float* w_mu0 = (const float*)d_in[2];
  const float* w_rho0 = (const float*)d_in[3];
  const float* b_mu0 = (const float*)d_in[4];
  const float* b_rho0 = (const float*)d_in[5];
  const float* w_eps0 = (const float*)d_in[6];
  const float* b_eps0 = (const float*)d_in[7];
  const float* w_mu1 = (const float*)d_in[8];
  const float* w_rho1 = (const float*)d_in[9];
  const float* b_mu1 = (const float*)d_in[10];
  const float* b_rho1 = (const float*)d_in[11];
  const float* w_eps1 = (const float*)d_in[12];
  const float* b_eps1 = (const float*)d_in[13];
  const float* w_mu2 = (const float*)d_in[14];
  const float* w_rho2 = (const float*)d_in[15];
  const float* b_mu2 = (const float*)d_in[16];
  const float* b_rho2 = (const float*)d_in[17];
  const float* w_eps2 = (const float*)d_in[18];
  const float* b_eps2 = (const float*)d_in[19];
  const float* uh_w1 = (const float*)d_in[20];
  const float* uh_b1 = (const float*)d_in[21];
  const float* uh_w2 = (const float*)d_in[22];
  const float* uh_b2 = (const float*)d_in[23];
  const float* rh_w1 = (const float*)d_in[24];
  const float* rh_b1 = (const float*)d_in[25];
  const float* rh_w2 = (const float*)d_in[26];
  const float* rh_b2 = (const float*)d_in[27];
  float* out = (float*)d_out;

  char* ws = (char*)d_ws;
  unsigned short* stateb = (unsigned short*)ws;          // 2 MB
  char* W0f = ws + 2097152;                              // 6.5536 MB
  char* W1f = W0f + 6553600;
  char* W2f = W1f + 6553600;                             // 0.8192 MB
  float* bias0 = (float*)(W2f + 819200);                 // 12800 f
  float* bias1 = bias0 + 12800;
  float* bias2 = bias1 + 12800;                          // 1600 f
  float* y2 = bias2 + 1600;                              // 4096*1000 f
  float* klpart = y2 + (size_t)4096 * 1000;              // 4019 f

  prep_kernel<<<4019, 256, 0, stream>>>(
      state, stateb, w_mu0, w_rho0, w_eps0, W0f, w_mu1, w_rho1, w_eps1, W1f,
      w_mu2, w_rho2, w_eps2, W2f, b_mu0, b_rho0, b_eps0, b_mu1, b_rho1, b_eps1,
      b_mu2, b_rho2, b_eps2, bias0, bias1, bias2, klpart);
  mlp_fused<<<800, 512, 0, stream>>>(stateb, W0f, W1f, W2f, bias0, bias1,
                                     bias2, y2);
  heads_kernel<<<4097, 256, 0, stream>>>(y2, klpart, uh_w1, uh_b1, uh_w2, uh_b2,
                                         rh_w1, rh_b1, rh_w2, rh_b2, out);
}

// Round 5
// 137.417 us; speedup vs baseline: 1.0877x; 1.0877x over previous
//
#include <hip/hip_runtime.h>
#include <hip/hip_bf16.h>

// ---------------------------------------------------------------------------
// UncertaintyAwareQNetwork: E=5 ensemble x NS=10 MC samples, B=4096 rows.
// Pipeline (3 dispatches):
//   prep:   state->bf16, realized weights (MFMA-frag-major, vectorized loads)
//           + fused KL partials
//   mlp:    fused 3-layer MFMA kernel, 128-row x 256-out block tile, 64 KB LDS
//           (2 blocks/CU), 8 waves = 2 row-groups x 4 o-groups, 64x64 wave tile
//   heads:  ensemble stats + uncertainty/risk heads + KL final
// y2 layout: [b][es*20 + o] f32 (row = 1000 floats) for coalesced heads reads.
// ---------------------------------------------------------------------------

typedef __bf16 bf16x8 __attribute__((ext_vector_type(8)));
typedef float f32x4 __attribute__((ext_vector_type(4)));
typedef unsigned short u16x4 __attribute__((ext_vector_type(4)));
typedef unsigned short u16x8 __attribute__((ext_vector_type(8)));

__device__ __forceinline__ unsigned short f2bf(float f) {
  unsigned int u = __builtin_bit_cast(unsigned int, f);
  u += 0x7fffu + ((u >> 16) & 1u);
  return (unsigned short)(u >> 16);
}

__device__ __forceinline__ float softplus_f(float x) {
  return (x > 20.f) ? x : __logf(1.f + __expf(x));
}

__device__ __forceinline__ float klterm(float m, float sg) {
  return -__logf(sg) + (sg * sg + m * m) * 0.5f - 0.5f;
}

__device__ __forceinline__ f32x4 mfma16(bf16x8 a, bf16x8 b, f32x4 c) {
  return __builtin_amdgcn_mfma_f32_16x16x32_bf16(a, b, c, 0, 0, 0);
}

// ------------------- prep bodies (fused into one kernel) --------------------

__device__ __forceinline__ void scvt_body(int gid, const float* __restrict__ s,
                                          unsigned short* __restrict__ d) {
  const f32x4* p = (const f32x4*)(s + (size_t)gid * 8);
  f32x4 x0 = p[0], x1 = p[1];
  u16x8 v = {f2bf(x0.x), f2bf(x0.y), f2bf(x0.z), f2bf(x0.w),
             f2bf(x1.x), f2bf(x1.y), f2bf(x1.z), f2bf(x1.w)};
  *(u16x8*)(d + (size_t)gid * 8) = v;
}

// frag id = (es*(OPAD/16) + osub)*8 + kt ; lane l holds
// W[o = osub*16 + l%16][i = kt*32 + (l/16)*8 + 0..7]
// Returns this thread's KL partial (counted only for s==0 to avoid 10x).
template <int O, int OPAD>
__device__ __forceinline__ float wgen_body(int gid, const float* __restrict__ wmu,
                                           const float* __restrict__ wrho,
                                           const float* __restrict__ weps,
                                           char* __restrict__ wf) {
  int es = gid / (OPAD * 32);
  int rem = gid - es * (OPAD * 32);
  int o = rem >> 5;
  int i8 = (rem & 31) * 8;
  int e = es / 10, s = es - e * 10;
  float v[8];
  float kl = 0.f;
  if (O == OPAD || o < O) {
    const float* mu = wmu + ((size_t)(e * O + o)) * 256 + i8;
    const float* rho = wrho + ((size_t)(e * O + o)) * 256 + i8;
    const float* eps = weps + ((size_t)((e * 10 + s) * O + o)) * 256 + i8;
    float mv[8], rv[8], ev[8];
    *(f32x4*)(mv) = ((const f32x4*)mu)[0];
    *(f32x4*)(mv + 4) = ((const f32x4*)mu)[1];
    *(f32x4*)(rv) = ((const f32x4*)rho)[0];
    *(f32x4*)(rv + 4) = ((const f32x4*)rho)[1];
    *(f32x4*)(ev) = ((const f32x4*)eps)[0];
    *(f32x4*)(ev + 4) = ((const f32x4*)eps)[1];
#pragma unroll
    for (int j = 0; j < 8; ++j) {
      float m = mv[j];
      float sg = softplus_f(rv[j]);
      v[j] = m + sg * ev[j];
      if (s == 0) kl += klterm(m, sg);
    }
  } else {
#pragma unroll
    for (int j = 0; j < 8; ++j) v[j] = 0.f;
  }
  u16x8 pk = {f2bf(v[0]), f2bf(v[1]), f2bf(v[2]), f2bf(v[3]),
              f2bf(v[4]), f2bf(v[5]), f2bf(v[6]), f2bf(v[7])};
  int osub = o >> 4, om = o & 15, kt = i8 >> 5, jj = (i8 >> 3) & 3;
  int lane = jj * 16 + om;
  *(u16x8*)(wf + (size_t)(((es * (OPAD / 16) + osub) * 8 + kt) * 64 + lane) * 16) = pk;
  return kl;
}

__global__ __launch_bounds__(256) void prep_kernel(
    const float* __restrict__ state, unsigned short* __restrict__ stateb,
    const float* __restrict__ wmu0, const float* __restrict__ wrho0,
    const float* __restrict__ weps0, char* __restrict__ W0f,
    const float* __restrict__ wmu1, const float* __restrict__ wrho1,
    const float* __restrict__ weps1, char* __restrict__ W1f,
    const float* __restrict__ wmu2, const float* __restrict__ wrho2,
    const float* __restrict__ weps2, char* __restrict__ W2f,
    const float* __restrict__ bmu0, const float* __restrict__ brho0,
    const float* __restrict__ beps0, const float* __restrict__ bmu1,
    const float* __restrict__ brho1, const float* __restrict__ beps1,
    const float* __restrict__ bmu2, const float* __restrict__ brho2,
    const float* __restrict__ beps2, float* __restrict__ bias0,
    float* __restrict__ bias1, float* __restrict__ bias2,
    float* __restrict__ partials) {
  int bid = blockIdx.x, t = threadIdx.x;
  float kl = 0.f;
  if (bid < 512) {
    scvt_body(bid * 256 + t, state, stateb);
  } else if (bid < 2112) {
    kl = wgen_body<256, 256>((bid - 512) * 256 + t, wmu0, wrho0, weps0, W0f);
  } else if (bid < 3712) {
    kl = wgen_body<256, 256>((bid - 2112) * 256 + t, wmu1, wrho1, weps1, W1f);
  } else if (bid < 3912) {
    kl = wgen_body<18, 32>((bid - 3712) * 256 + t, wmu2, wrho2, weps2, W2f);
  } else {
    int gid = (bid - 3912) * 256 + t;
    if (gid < 12800) {
      int es = gid >> 8, o = gid & 255, e = es / 10, s = es - e * 10;
      float m = bmu0[e * 256 + o];
      float sg = softplus_f(brho0[e * 256 + o]);
      bias0[gid] = m + sg * beps0[(e * 10 + s) * 256 + o];
      if (s == 0) kl = klterm(m, sg);
    } else if (gid < 25600) {
      int id = gid - 12800;
      int es = id >> 8, o = id & 255, e = es / 10, s = es - e * 10;
      float m = bmu1[e * 256 + o];
      float sg = softplus_f(brho1[e * 256 + o]);
      bias1[id] = m + sg * beps1[(e * 10 + s) * 256 + o];
      if (s == 0) kl = klterm(m, sg);
    } else if (gid < 27200) {
      int id = gid - 25600;
      int es = id >> 5, o = id & 31, e = es / 10, s = es - e * 10;
      if (o < 18) {
        float m = bmu2[e * 18 + o];
        float sg = softplus_f(brho2[e * 18 + o]);
        bias2[id] = m + sg * beps2[(e * 10 + s) * 18 + o];
        if (s == 0) kl = klterm(m, sg);
      } else {
        bias2[id] = 0.f;
      }
    }
  }
  // uniform block reduce of kl partials
#pragma unroll
  for (int m = 32; m >= 1; m >>= 1) kl += __shfl_xor(kl, m);
  __shared__ float wsum[4];
  if ((t & 63) == 0) wsum[t >> 6] = kl;
  __syncthreads();
  if (t == 0) partials[bid] = wsum[0] + wsum[1] + wsum[2] + wsum[3];
}

// ------------------------------ fused MLP ------------------------------------
// Block tile: 128 rows x 256 outs in 64 KB LDS (2 blocks/CU). 8 waves =
// 2 row-groups (bg) x 4 o-groups (og); wave tile 64 outs x 64 rows ->
// acc[4][4]. Weights (A-frags) stream from L2; activations (B-frags) from
// LDS, overwritten in place between layers.
__device__ __forceinline__ void mlp_layer128(const char* __restrict__ wf_og,
                                             const float* __restrict__ bias_es,
                                             int obase, char* __restrict__ bufh,
                                             int lane) {
  f32x4 acc[4][4];
  f32x4 zero = {0.f, 0.f, 0.f, 0.f};
#pragma unroll
  for (int ot = 0; ot < 4; ++ot)
#pragma unroll
    for (int bt = 0; bt < 4; ++bt) acc[ot][bt] = zero;

#pragma unroll
  for (int kt = 0; kt < 8; ++kt) {
    bf16x8 bfr[4], afr[4];
#pragma unroll
    for (int bt = 0; bt < 4; ++bt)
      bfr[bt] = *(const bf16x8*)(bufh + (bt * 8 + kt) * 1024 + lane * 16);
#pragma unroll
    for (int ot = 0; ot < 4; ++ot)
      afr[ot] = *(const bf16x8*)(wf_og + (ot * 8 + kt) * 1024 + lane * 16);
    __builtin_amdgcn_s_setprio(1);
#pragma unroll
    for (int ot = 0; ot < 4; ++ot)
#pragma unroll
      for (int bt = 0; bt < 4; ++bt)
        acc[ot][bt] = mfma16(afr[ot], bfr[bt], acc[ot][bt]);
    __builtin_amdgcn_s_setprio(0);
  }
  __syncthreads();  // all reads of buf complete before in-place overwrite

  int g = lane >> 4, lm = lane & 15;
#pragma unroll
  for (int ot = 0; ot < 4; ++ot) {
    int i0 = obase + ot * 16 + 4 * g;
    f32x4 bv = *(const f32x4*)(bias_es + i0);
    int ktp = i0 >> 5;
    int lanep = ((i0 & 31) >> 3) * 16 + lm;
    int byo = (i0 & 7) * 2;
#pragma unroll
    for (int bt = 0; bt < 4; ++bt) {
      float v0 = fmaxf(acc[ot][bt].x + bv.x, 0.f);
      float v1 = fmaxf(acc[ot][bt].y + bv.y, 0.f);
      float v2 = fmaxf(acc[ot][bt].z + bv.z, 0.f);
      float v3 = fmaxf(acc[ot][bt].w + bv.w, 0.f);
      u16x4 pk = {f2bf(v0), f2bf(v1), f2bf(v2), f2bf(v3)};
      *(u16x4*)(bufh + (bt * 8 + ktp) * 1024 + lanep * 16 + byo) = pk;
    }
  }
  __syncthreads();  // writes visible before next layer reads
}

__global__ __launch_bounds__(512, 4) void mlp_fused(
    const unsigned short* __restrict__ stateb, const char* __restrict__ W0f,
    const char* __restrict__ W1f, const char* __restrict__ W2f,
    const float* __restrict__ bias0, const float* __restrict__ bias1,
    const float* __restrict__ bias2, float* __restrict__ y2) {
  __shared__ char buf[65536];  // 128 rows x 256 cols bf16 as 64 1KB frags
  int tid = threadIdx.x, w = tid >> 6, lane = tid & 63;

  // XCD-chunked bijective swizzle: 1600 = 8 XCD * 200; same-es blocks share L2.
  int bid = blockIdx.x;
  int lin = (bid & 7) * 200 + (bid >> 3);
  int es = lin >> 5, b0 = (lin & 31) * 128;
  int og = w & 3, bg = w >> 2;

  // stage state tile [128 rows][256] as 64 B-frags
#pragma unroll
  for (int it = 0; it < 8; ++it) {
    int F = it * 8 + w, bt = F >> 3, kt = F & 7;
    const unsigned short* src =
        stateb + (size_t)(b0 + bt * 16 + (lane & 15)) * 256 + kt * 32 + (lane >> 4) * 8;
    *(u16x8*)(buf + F * 1024 + lane * 16) = *(const u16x8*)src;
  }
  __syncthreads();

  char* bufh = buf + bg * 32768;  // this wave's 64-row half
  mlp_layer128(W0f + (size_t)(es * 16 + og * 4) * 8192, bias0 + es * 256,
               og * 64, bufh, lane);
  mlp_layer128(W1f + (size_t)(es * 16 + og * 4) * 8192, bias1 + es * 256,
               og * 64, bufh, lane);

  // layer 2: O padded to 32; wave w handles row-subtile bt=w (16 rows), both osub
  f32x4 zero = {0.f, 0.f, 0.f, 0.f};
  f32x4 acc2[2] = {zero, zero};
  const char* w2 = W2f + (size_t)es * 16384;
#pragma unroll
  for (int kt = 0; kt < 8; ++kt) {
    bf16x8 b = *(const bf16x8*)(buf + (w * 8 + kt) * 1024 + lane * 16);
    bf16x8 a0 = *(const bf16x8*)(w2 + kt * 1024 + lane * 16);
    bf16x8 a1 = *(const bf16x8*)(w2 + (8 + kt) * 1024 + lane * 16);
    acc2[0] = mfma16(a0, b, acc2[0]);
    acc2[1] = mfma16(a1, b, acc2[1]);
  }
  int g = lane >> 4, lm = lane & 15;
  int b_idx = b0 + w * 16 + lm;
  f32x4 bv0 = *(const f32x4*)(bias2 + es * 32 + 4 * g);
  float b16 = bias2[es * 32 + 16], b17 = bias2[es * 32 + 17];
  f32x4 o4 = {acc2[0].x + bv0.x, acc2[0].y + bv0.y, acc2[0].z + bv0.z,
              acc2[0].w + bv0.w};
  *(f32x4*)(y2 + (size_t)b_idx * 1000 + es * 20 + 4 * g) = o4;
  if (g == 0) {
    float2 o2 = {acc2[1].x + b16, acc2[1].y + b17};
    *(float2*)(y2 + (size_t)b_idx * 1000 + es * 20 + 16) = o2;
  }
}

// ------------- heads (with fused ensemble stats + KL final) ------------------
__global__ __launch_bounds__(256) void heads_kernel(
    const float* __restrict__ y2, const float* __restrict__ partials,
    const float* __restrict__ uh_w1, const float* __restrict__ uh_b1,
    const float* __restrict__ uh_w2, const float* __restrict__ uh_b2,
    const float* __restrict__ rh_w1, const float* __restrict__ rh_b1,
    const float* __restrict__ rh_w2, const float* __restrict__ rh_b2,
    float* __restrict__ out) {
  int b = blockIdx.x, t = threadIdx.x;
  if (b == 4096) {  // KL final reduce
    if (t < 64) {
      float acc = 0.f;
      for (int i = t; i < 4019; i += 64) acc += partials[i];
#pragma unroll
      for (int m = 32; m >= 1; m >>= 1) acc += __shfl_xor(acc, m);
      if (t == 0) out[446464] = acc * 0.2f;
    }
    return;
  }

  __shared__ float ysh[1000];
  __shared__ float qsE[90];
  __shared__ float rin[54];
  __shared__ float h[256];

  // coalesced row load: 1000 floats
  if (t < 250) *(f32x4*)(ysh + t * 4) = *(const f32x4*)(y2 + (size_t)b * 1000 + t * 4);
  __syncthreads();

  // per-(a,e) MC mean over s
  if (t < 90) {
    int a = t / 5, e = t - (t / 5) * 5;
    float v = 0.f;
#pragma unroll
    for (int s = 0; s < 10; ++s) v += ysh[(e * 10 + s) * 20 + a];
    qsE[t] = v * 0.1f;
  }
  __syncthreads();
  if (t < 18) {
    float qs = 0.f, qq = 0.f;
#pragma unroll
    for (int e = 0; e < 5; ++e) {
      float v = qsE[t * 5 + e];
      qs += v;
      qq += v * v;
    }
    float mean = qs * 0.2f;
    float var = fmaxf((qq - 5.f * mean * mean) * 0.25f, 0.f);
    rin[t] = mean;
    rin[18 + t] = var;
    out[b * 18 + t] = mean;
    out[73728 + b * 18 + t] = var;
  }
  __syncthreads();

  // uncertainty hidden layer
  {
    float acc = uh_b1[t];
    const f32x4* wr = (const f32x4*)(uh_w1 + t * 36);
#pragma unroll
    for (int j = 0; j < 9; ++j) {
      f32x4 wv = wr[j];
      acc += wv.x * rin[j * 4] + wv.y * rin[j * 4 + 1] + wv.z * rin[j * 4 + 2] +
             wv.w * rin[j * 4 + 3];
    }
    h[t] = fmaxf(acc, 0.f);
  }
  __syncthreads();

  int w = t >> 6, lane = t & 63;
  for (int idx = 0; idx < 5; ++idx) {
    int a = idx * 4 + w;
    if (a < 18) {
      float p = 0.f;
#pragma unroll
      for (int j = 0; j < 4; ++j) p += h[lane + 64 * j] * uh_w2[a * 256 + lane + 64 * j];
#pragma unroll
      for (int m = 32; m >= 1; m >>= 1) p += __shfl_xor(p, m);
      if (lane == 0) {
        float alea = softplus_f(p + uh_b2[a]);
        float qm = rin[a], epi = rin[18 + a];
        float tu = epi + alea;
        float s2 = 2.f * sqrtf(tu);
        out[2 * 73728 + b * 18 + a] = alea;
        out[3 * 73728 + b * 18 + a] = tu;
        out[4 * 73728 + b * 18 + a] = qm - s2;
        out[5 * 73728 + b * 18 + a] = qm + s2;
        rin[36 + a] = alea;
      }
    }
  }
  __syncthreads();

  // risk hidden layer
  {
    float acc = rh_b1[t];
    const float2* wr2 = (const float2*)(rh_w1 + t * 54);
#pragma unroll
    for (int j = 0; j < 27; ++j) {
      float2 wv = wr2[j];
      acc += wv.x * rin[j * 2] + wv.y * rin[j * 2 + 1];
    }
    h[t] = fmaxf(acc, 0.f);
  }
  __syncthreads();
  if (w == 0) {
    float p = 0.f;
#pragma unroll
    for (int j = 0; j < 4; ++j) p += h[lane + 64 * j] * rh_w2[lane + 64 * j];
#pragma unroll
    for (int m = 32; m >= 1; m >>= 1) p += __shfl_xor(p, m);
    if (lane == 0) out[6 * 73728 + b] = p + rh_b2[0];
  }
}

// ------------------------------ launch ---------------------------------------
extern "C" void kernel_launch(void* const* d_in, const int* in_sizes, int n_in,
                              void* d_out, int out_size, void* d_ws, size_t ws_size,
                              hipStream_t stream) {
  const float* state = (const float*)d_in[0];
  const float* w_mu0 = (const float*)d_in[2];
  const float* w_rho0 = (const float*)d_in[3];
  const float* b_mu0 = (const float*)d_in[4];
  const float* b_rho0 = (const float*)d_in[5];
  const float* w_eps0 = (const float*)d_in[6];
  const float* b_eps0 = (const float*)d_in[7];
  const float* w_mu1 = (const float*)d_in[8];
  const float* w_rho1 = (const float*)d_in[9];
  const float* b_mu1 = (const float*)d_in[10];
  const float* b_rho1 = (const float*)d_in[11];
  const float* w_eps1 = (const float*)d_in[12];
  const float* b_eps1 = (const float*)d_in[13];
  const float* w_mu2 = (const float*)d_in[14];
  const float* w_rho2 = (const float*)d_in[15];
  const float* b_mu2 = (const float*)d_in[16];
  const float* b_rho2 = (const float*)d_in[17];
  const float* w_eps2 = (const float*)d_in[18];
  const float* b_eps2 = (const float*)d_in[19];
  const float* uh_w1 = (const float*)d_in[20];
  const float* uh_b1 = (const float*)d_in[21];
  const float* uh_w2 = (const float*)d_in[22];
  const float* uh_b2 = (const float*)d_in[23];
  const float* rh_w1 = (const float*)d_in[24];
  const float* rh_b1 = (const float*)d_in[25];
  const float* rh_w2 = (const float*)d_in[26];
  const float* rh_b2 = (const float*)d_in[27];
  float* out = (float*)d_out;

  char* ws = (char*)d_ws;
  unsigned short* stateb = (unsigned short*)ws;          // 2 MB
  char* W0f = ws + 2097152;                              // 6.5536 MB
  char* W1f = W0f + 6553600;
  char* W2f = W1f + 6553600;                             // 0.8192 MB
  float* bias0 = (float*)(W2f + 819200);                 // 12800 f
  float* bias1 = bias0 + 12800;
  float* bias2 = bias1 + 12800;                          // 1600 f
  float* y2 = bias2 + 1600;                              // 4096*1000 f
  float* klpart = y2 + (size_t)4096 * 1000;              // 4019 f

  prep_kernel<<<4019, 256, 0, stream>>>(
      state, stateb, w_mu0, w_rho0, w_eps0, W0f, w_mu1, w_rho1, w_eps1, W1f,
      w_mu2, w_rho2, w_eps2, W2f, b_mu0, b_rho0, b_eps0, b_mu1, b_rho1, b_eps1,
      b_mu2, b_rho2, b_eps2, bias0, bias1, bias2, klpart);
  mlp_fused<<<1600, 512, 0, stream>>>(stateb, W0f, W1f, W2f, bias0, bias1,
                                      bias2, y2);
  heads_kernel<<<4097, 256, 0, stream>>>(y2, klpart, uh_w1, uh_b1, uh_w2, uh_b2,
                                         rh_w1, rh_b1, rh_w2, rh_b2, out);
}